// Round 1
// 370.728 us; speedup vs baseline: 1.0158x; 1.0158x over previous
//
#include <hip/hip_runtime.h>

#define B_SZ 2048
#define T_SZ 2048
#define LOG2E 1.44269504088896340736f

// Fused single-kernel GRU:
//   128 blocks x 128 threads. Per block: 16 batch rows.
//   wave 0 = consumer: sequential scan, 4 lanes/row (u=0,1,2 + spare).
//   wave 1 = producer: computes pre-scaled activation records for chunk c+1
//            into an LDS double buffer while consumer scans chunk c.
// Record (fp32, LDS): per (row, t, u): float4 { Az_u, Ar_u, Xh_u, m }
//   Az = -log2e*(xw_z + bi_z + br_z)   -> z  = rcp(1 + 2^(Az + h.Rz))
//   Ar = -log2e*(xw_r + bi_r + br_r)   -> r  = rcp(1 + 2^(Ar + h.Rr))
//   Xh = 2*log2e*(xw_h + bi_h)         -> hc = 1 - 2*rcp(1 + 2^(Xh + r*hh))
//   m  = any(x[b,t,:] != 0)
// No fp16 anywhere; rec never touches HBM.

#define ROWS 16u
#define CHUNK 16u
#define NCHUNK 128u
#define ROWSTRIDE 784u            // 16 t * 48 B + 16 B pad (breaks bank aliasing)
#define BUFSTRIDE (16u * ROWSTRIDE)  // 12544 B per buffer

// quad_perm DPP broadcast/butterfly (all lanes active at call sites)
template <int CTRL>
static __device__ __forceinline__ float bcast(float v) {
  return __builtin_bit_cast(float,
      __builtin_amdgcn_mov_dpp(__builtin_bit_cast(int, v), CTRL, 0xF, 0xF, false));
}

// ---------------- producer: one (row, t) record -> 3 float4 in LDS ----------
#define PREC(va, vb, dst)                                                   \
  do {                                                                      \
    float xr[8] = {(va).x, (va).y, (va).z, (va).w,                          \
                   (vb).x, (vb).y, (vb).z, (vb).w};                         \
    float A[9];                                                             \
    _Pragma("unroll") for (int c_ = 0; c_ < 9; c_++) {                      \
      float acc = xr[0] * K[0 * 9 + c_];                                    \
      _Pragma("unroll") for (int f_ = 1; f_ < 8; f_++)                      \
          acc = fmaf(xr[f_], K[f_ * 9 + c_], acc);                          \
      float sc_ = (c_ < 6) ? -LOG2E : 2.0f * LOG2E;                         \
      A[c_] = fmaf(sc_, acc, off[c_]);                                      \
    }                                                                       \
    bool any_ = false;                                                      \
    _Pragma("unroll") for (int f_ = 0; f_ < 8; f_++)                        \
        any_ = any_ || (xr[f_] != 0.0f);                                    \
    float mf_ = any_ ? 1.0f : 0.0f;                                         \
    ((float4*)(dst))[0] = make_float4(A[0], A[3], A[6], mf_);               \
    ((float4*)(dst))[1] = make_float4(A[1], A[4], A[7], mf_);               \
    ((float4*)(dst))[2] = make_float4(A[2], A[5], A[8], mf_);               \
  } while (0)

// producer lane (r = lane&15, tt = lane>>4) does 4 consecutive timesteps:
// 128 B contiguous x read per lane, 12 ds_write_b128.
#define PRODUCE(cc)                                                         \
  do {                                                                      \
    const float4* _xp = xrow + (size_t)((cc)*CHUNK + tt * 4u) * 2u;         \
    float4 v0 = _xp[0], v1 = _xp[1], v2 = _xp[2], v3 = _xp[3];              \
    float4 v4 = _xp[4], v5 = _xp[5], v6 = _xp[6], v7 = _xp[7];              \
    char* _d = lds + ((cc)&1u) * BUFSTRIDE + r * ROWSTRIDE + tt * 4u * 48u; \
    PREC(v0, v1, _d + 0 * 48);                                              \
    PREC(v2, v3, _d + 1 * 48);                                              \
    PREC(v4, v5, _d + 2 * 48);                                              \
    PREC(v6, v7, _d + 3 * 48);                                              \
  } while (0)

// ---------------- consumer: 16-step chunk, named registers -----------------
#define DECL16(P)                                                           \
  float4 P##0, P##1, P##2, P##3, P##4, P##5, P##6, P##7, P##8, P##9,        \
      P##10, P##11, P##12, P##13, P##14, P##15

#define LLOAD16(P, qp)                                                      \
  do {                                                                      \
    const char* _q = (qp);                                                  \
    P##0 = *(const float4*)(_q + 0 * 48);                                   \
    P##1 = *(const float4*)(_q + 1 * 48);                                   \
    P##2 = *(const float4*)(_q + 2 * 48);                                   \
    P##3 = *(const float4*)(_q + 3 * 48);                                   \
    P##4 = *(const float4*)(_q + 4 * 48);                                   \
    P##5 = *(const float4*)(_q + 5 * 48);                                   \
    P##6 = *(const float4*)(_q + 6 * 48);                                   \
    P##7 = *(const float4*)(_q + 7 * 48);                                   \
    P##8 = *(const float4*)(_q + 8 * 48);                                   \
    P##9 = *(const float4*)(_q + 9 * 48);                                   \
    P##10 = *(const float4*)(_q + 10 * 48);                                 \
    P##11 = *(const float4*)(_q + 11 * 48);                                 \
    P##12 = *(const float4*)(_q + 12 * 48);                                 \
    P##13 = *(const float4*)(_q + 13 * 48);                                 \
    P##14 = *(const float4*)(_q + 14 * 48);                                 \
    P##15 = *(const float4*)(_q + 15 * 48);                                 \
  } while (0)

#define STEP(J, C, tb)                                                      \
  do {                                                                      \
    float h0 = bcast<0x00>(h);                                              \
    float h1 = bcast<0x55>(h);                                              \
    float h2 = bcast<0xAA>(h);                                              \
    float tz = fmaf(h0, Rz0, (C).x); tz = fmaf(h1, Rz1, tz);                \
    tz = fmaf(h2, Rz2, tz);                                                 \
    float tr = fmaf(h0, Rr0, (C).y); tr = fmaf(h1, Rr1, tr);                \
    tr = fmaf(h2, Rr2, tr);                                                 \
    float hh = fmaf(h0, Rh0, Ch); hh = fmaf(h1, Rh1, hh);                   \
    hh = fmaf(h2, Rh2, hh);                                                 \
    float z = __builtin_amdgcn_rcpf(1.0f + __builtin_amdgcn_exp2f(tz));     \
    float rr = __builtin_amdgcn_rcpf(1.0f + __builtin_amdgcn_exp2f(tr));    \
    float arg = fmaf(rr, hh, (C).z);                                        \
    float qd = __builtin_amdgcn_rcpf(1.0f + __builtin_amdgcn_exp2f(arg));   \
    float hc = fmaf(-2.0f, qd, 1.0f);                                       \
    float t1 = hc - h;                                                      \
    float s = fmaf(-z, t1, t1);                                             \
    h = fmaf((C).w, s, h); /* h_new; == h_full when m=1, else h_old */      \
    float pp = h * wl;     /* m=1: h_full.w ; m=0: ov=db anyway */          \
    pp += bcast<0xB1>(pp);                                                  \
    pp += bcast<0x4E>(pp);                                                  \
    float ov = fmaf((C).w, pp, dbv);                                        \
    if (((J)&3) == 0) o0 = ov;                                              \
    else if (((J)&3) == 1) o1 = ov;                                         \
    else if (((J)&3) == 2) o2 = ov;                                         \
    else if (u == 0) {                                                      \
      float4 v_; v_.x = o0; v_.y = o1; v_.z = o2; v_.w = ov;                \
      *(float4*)(out + outbase + (tb) + (J) - 3) = v_;                      \
    }                                                                       \
  } while (0)

#define COMPUTE16(P, tb)                                                    \
  do {                                                                      \
    STEP(0, P##0, tb);  STEP(1, P##1, tb);  STEP(2, P##2, tb);              \
    STEP(3, P##3, tb);  STEP(4, P##4, tb);  STEP(5, P##5, tb);              \
    STEP(6, P##6, tb);  STEP(7, P##7, tb);  STEP(8, P##8, tb);              \
    STEP(9, P##9, tb);  STEP(10, P##10, tb); STEP(11, P##11, tb);           \
    STEP(12, P##12, tb); STEP(13, P##13, tb); STEP(14, P##14, tb);          \
    STEP(15, P##15, tb);                                                    \
  } while (0)

__global__ __launch_bounds__(128, 1) void gru_fused(
    const float* __restrict__ x, const float* __restrict__ kern,
    const float* __restrict__ rk, const float* __restrict__ bi,
    const float* __restrict__ br, const float* __restrict__ dw,
    const float* __restrict__ db, float* __restrict__ out) {
  __shared__ float4 lds4[2u * BUFSTRIDE / 16u];
  char* lds = (char*)lds4;

  const unsigned tid = threadIdx.x;
  const unsigned wv = tid >> 6;     // 0 = consumer (scan), 1 = producer
  const unsigned lane = tid & 63u;
  const unsigned b0 = blockIdx.x * ROWS;

  // producer state
  float K[72];
  float off[9];
  const float4* xrow = nullptr;
  const unsigned r = lane & 15u;
  const unsigned tt = lane >> 4;    // 0..3

  // consumer state
  const unsigned q = lane >> 2;     // row within block
  const unsigned u = lane & 3u;     // hidden unit (3 = spare)
  float Rz0 = 0, Rz1 = 0, Rz2 = 0, Rr0 = 0, Rr1 = 0, Rr2 = 0;
  float Rh0 = 0, Rh1 = 0, Rh2 = 0, Ch = 0, wl = 0, dbv = 0;
  size_t outbase = 0;
  unsigned cbo = 0;
  float h = 0, o0 = 0, o1 = 0, o2 = 0;

  if (wv == 1u) {
    const float4* kp = (const float4*)kern;  // 72 floats = 18 float4
#pragma unroll
    for (int i = 0; i < 18; i++) {
      float4 v = kp[i];
      K[4 * i + 0] = v.x; K[4 * i + 1] = v.y;
      K[4 * i + 2] = v.z; K[4 * i + 3] = v.w;
    }
#pragma unroll
    for (int c = 0; c < 9; c++)
      off[c] = (c < 6) ? (-LOG2E * (bi[c] + br[c])) : (2.0f * LOG2E * bi[c]);
    xrow = (const float4*)(x + (size_t)(b0 + r) * T_SZ * 8u);
    PRODUCE(0u);                    // prologue: fill chunk 0
  } else {
    if (u < 3u) {
      Rz0 = -LOG2E * rk[0 * 9 + u];
      Rz1 = -LOG2E * rk[1 * 9 + u];
      Rz2 = -LOG2E * rk[2 * 9 + u];
      Rr0 = -LOG2E * rk[0 * 9 + 3 + u];
      Rr1 = -LOG2E * rk[1 * 9 + 3 + u];
      Rr2 = -LOG2E * rk[2 * 9 + 3 + u];
      Rh0 = 2.0f * LOG2E * rk[0 * 9 + 6 + u];
      Rh1 = 2.0f * LOG2E * rk[1 * 9 + 6 + u];
      Rh2 = 2.0f * LOG2E * rk[2 * 9 + 6 + u];
      Ch = 2.0f * LOG2E * br[6 + u];
      wl = dw[u];                   // lane3: wl=0 -> contributes 0 to quad dot
    }
    dbv = db[0];
    unsigned u2 = (u < 3u) ? u : 2u;  // lane3 reads u=2 slot (LDS broadcast)
    outbase = (size_t)(b0 + q) * T_SZ;
    cbo = q * ROWSTRIDE + u2 * 16u;
  }

  __syncthreads();                  // chunk 0 ready

  for (unsigned c = 0; c < NCHUNK; ++c) {
    if (wv == 1u) {
      if (c + 1u < NCHUNK) PRODUCE(c + 1u);  // fill other buffer
    } else {
      const char* cb = lds + (c & 1u) * BUFSTRIDE + cbo;
      DECL16(A);
      LLOAD16(A, cb);
      COMPUTE16(A, c * CHUNK);
    }
    __syncthreads();                // producer done c+1, consumer done c
  }
}

// ---------------------------------------------------------------------------
extern "C" void kernel_launch(void* const* d_in, const int* in_sizes, int n_in,
                              void* d_out, int out_size, void* d_ws,
                              size_t ws_size, hipStream_t stream) {
  const float* x  = (const float*)d_in[0];
  const float* k  = (const float*)d_in[1];
  const float* rk = (const float*)d_in[2];
  const float* bi = (const float*)d_in[3];
  const float* br = (const float*)d_in[4];
  const float* dw = (const float*)d_in[5];
  const float* db = (const float*)d_in[6];
  float* out = (float*)d_out;

  hipLaunchKernelGGL(gru_fused, dim3(B_SZ / ROWS), dim3(128), 0, stream,
                     x, k, rk, bi, br, dw, db, out);
}